// Round 14
// baseline (942.984 us; speedup 1.0000x reference)
//
#include <hip/hip_runtime.h>

#define NN 100000
#define NE 1600000
#define DIN 128
#define DHID 256
#define DOUT 128
#define CAP 64          // fixed csr row capacity; P(deg>64) ~ 3e-14 for Poisson(16)

typedef unsigned int u32;
typedef unsigned short u16;

typedef __bf16 bf16x8 __attribute__((ext_vector_type(8)));
typedef float  f32x4  __attribute__((ext_vector_type(4)));

__device__ inline u16 f2bf(float f) {
    u32 u = __float_as_uint(f);
    u32 r = u + 0x7FFFu + ((u >> 16) & 1u);   // RTNE
    return (u16)(r >> 16);
}
__device__ inline u32 pack2(float a, float b) {
    return (u32)f2bf(a) | ((u32)f2bf(b) << 16);
}
__device__ inline float bflo(u32 u) { return __uint_as_float(u << 16); }
__device__ inline float bfhi(u32 u) { return __uint_as_float(u & 0xffff0000u); }

// ---------------- CSR build (one-pass, XCD-partitioned, fixed capacity) ----------------
__global__ void csr_build(const int* __restrict__ src, const int* __restrict__ dst,
                          int* __restrict__ fill, int* __restrict__ csrC, int nE) {
    int g  = blockIdx.x & 7;
    int bg = blockIdx.x >> 3;
    int nbg = gridDim.x >> 3;
    int lo = g * (NN / 8), hi = lo + (NN / 8);
    for (int e = bg * 256 + threadIdx.x; e < nE; e += nbg * 256) {
        int d = __builtin_nontemporal_load(dst + e);
        if (d >= lo && d < hi) {
            int pos = atomicAdd(&fill[d], 1);
            if (pos < CAP) csrC[(size_t)d * CAP + pos] = __builtin_nontemporal_load(src + e);
        }
    }
}

__global__ void invdeg_from_fill(const int* __restrict__ fill, float* __restrict__ invdeg, int n) {
    int i = blockIdx.x * 256 + threadIdx.x;
    if (i < n) { int d = fill[i]; invdeg[i] = d > 0 ? 1.0f / (float)d : 0.0f; }
}

// ---------------- conversions ----------------
__global__ void f32_to_bf16(const float4* __restrict__ in, uint2* __restrict__ outp, int total4) {
    int i = blockIdx.x * 256 + threadIdx.x;
    if (i < total4) {
        float4 v = in[i];
        uint2 r; r.x = pack2(v.x, v.y); r.y = pack2(v.z, v.w);
        outp[i] = r;
    }
}

__global__ void weights_to_bf16(const float4* __restrict__ W0, const float4* __restrict__ W1,
                                const float4* __restrict__ W2, const float4* __restrict__ W3,
                                const float4* __restrict__ W4, const float4* __restrict__ W5,
                                uint2* __restrict__ outp) {
    int i = blockIdx.x * 256 + threadIdx.x;
    if (i >= 65536) return;
    const float4* p; int off;
    if (i < 8192)       { p = W0; off = i; }
    else if (i < 16384) { p = W1; off = i - 8192; }
    else if (i < 32768) { p = W2; off = i - 16384; }
    else if (i < 49152) { p = W3; off = i - 32768; }
    else if (i < 57344) { p = W4; off = i - 49152; }
    else                { p = W5; off = i - 57344; }
    float4 v = p[off];
    uint2 r; r.x = pack2(v.x, v.y); r.y = pack2(v.z, v.w);
    outp[i] = r;
}

#define ACC8(A, U) \
    A[0] += bflo(U.x); A[1] += bfhi(U.x); A[2] += bflo(U.y); A[3] += bfhi(U.y); \
    A[4] += bflo(U.z); A[5] += bfhi(U.z); A[6] += bflo(U.w); A[7] += bfhi(U.w);

// ---------------- column-sliced XCD-affine pull-aggregation ----------------
// Row = NSL x 64B slices. Block b handles slice s = b % NSL -> with round-robin
// block->XCD dispatch, each XCD touches only its 64B column stripes: per-L2
// working set = total/NSL (51.2MB -> 6.4MB). One wave per (node, slice):
// 4 lanes per neighbor-row-slice -> 16 rows per load instruction.
template<int NSL>
__global__ __launch_bounds__(256)
void agg_sl(const uint4* __restrict__ feat,
            const int* __restrict__ fill, const float* __restrict__ invdeg,
            const int* __restrict__ csrC, uint4* __restrict__ aggOut) {
    int s = blockIdx.x % NSL;
    int chunk = blockIdx.x / NSL;
    int w = chunk * 4 + (threadIdx.x >> 6);
    int lane = threadIdx.x & 63;
    if (w >= NN) return;
    int dg = fill[w]; if (dg > CAP) dg = CAP;
    const int* cp = csrC + (size_t)w * CAP;
    int g = lane >> 2, sub = lane & 3;
    float a[8] = {0,0,0,0,0,0,0,0};
    for (int j = 0; j < dg; j += 16) {
        if (j + g < dg) {
            int sn = cp[j + g];
            uint4 u = feat[(size_t)sn * (NSL * 4) + s * 4 + sub];
            ACC8(a, u);
        }
    }
    float iv = invdeg[w];
#pragma unroll
    for (int i = 0; i < 8; ++i) {
        float v = a[i];
        v += __shfl_xor(v, 4);
        v += __shfl_xor(v, 8);
        v += __shfl_xor(v, 16);
        v += __shfl_xor(v, 32);
        a[i] = v * iv;
    }
    if (g == 0) {
        uint4 r;
        r.x = pack2(a[0], a[1]); r.y = pack2(a[2], a[3]);
        r.z = pack2(a[4], a[5]); r.w = pack2(a[6], a[7]);
        aggOut[(size_t)w * (NSL * 4) + s * 4 + sub] = r;
    }
}

// legacy 128-col gather with column offset (fallback path only)
template<int SH, int OFF>
__global__ __launch_bounds__(256)
void agg_bf16(const u32* __restrict__ feat,
              const int* __restrict__ fill, const float* __restrict__ invdeg,
              const int* __restrict__ csrC, u32* __restrict__ aggOut) {
    int w = (blockIdx.x * 256 + threadIdx.x) >> 6;
    int lane = threadIdx.x & 63;
    if (w >= NN) return;
    int dg = fill[w]; if (dg > CAP) dg = CAP;
    const int* cp = csrC + (size_t)w * CAP;
    float a0 = 0.f, b0 = 0.f, a1 = 0.f, b1 = 0.f;
    int j = 0;
    for (; j + 1 < dg; j += 2) {
        int s0 = cp[j], s1 = cp[j+1];
        u32 u0 = feat[((size_t)s0 << SH) + OFF + lane];
        u32 u1 = feat[((size_t)s1 << SH) + OFF + lane];
        a0 += bflo(u0); b0 += bfhi(u0);
        a1 += bflo(u1); b1 += bfhi(u1);
    }
    if (j < dg) {
        u32 u0 = feat[((size_t)cp[j] << SH) + OFF + lane];
        a0 += bflo(u0); b0 += bfhi(u0);
    }
    float iv = invdeg[w];
    aggOut[(size_t)w * 64 + lane] = pack2((a0 + a1) * iv, (b0 + b1) * iv);
}

// ---------------- MFMA bf16 dual-GEMM (templated block shape) ----------------
#define TM 128
#define TK 32
#define LDSTR 40   // bf16 elems per LDS row: 80 B (16B-aligned, low-conflict)

template<int NT, int TNN>
__device__ inline void mfma_pass_bf(const u16* __restrict__ A, int K, int lda,
                                    const u16* __restrict__ Wb, int ldw,
                                    int brow, int bcol, int n,
                                    int tid, int lane, int wr, int wc,
                                    u16* As, u16* Ws, f32x4 (&acc)[4][4])
{
    constexpr int ACH = (TM * TK) / (8 * NT);   // uint4 chunks per thread for A
    constexpr int WCH = (TNN * TK) / (8 * NT);  // for W
    int rsel = lane & 15;
    int krun = (lane >> 4) << 3;                // 0,8,16,24
    const uint4 zero4 = make_uint4(0u, 0u, 0u, 0u);
    uint4 av[ACH], wv[WCH];

#pragma unroll
    for (int i = 0; i < ACH; ++i) {
        int c = tid + i * NT, r = c >> 2, k8 = (c & 3) << 3;
        av[i] = (brow + r < n) ? *(const uint4*)(A + (size_t)(brow + r) * lda + k8) : zero4;
    }
#pragma unroll
    for (int i = 0; i < WCH; ++i) {
        int c = tid + i * NT, r = c >> 2, k8 = (c & 3) << 3;
        wv[i] = *(const uint4*)(Wb + (size_t)(bcol + r) * ldw + k8);
    }

    for (int kt = 0; kt < K; kt += TK) {
        __syncthreads();                        // prev-iter LDS reads done
#pragma unroll
        for (int i = 0; i < ACH; ++i) {
            int c = tid + i * NT, r = c >> 2, k8 = (c & 3) << 3;
            *(uint4*)&As[r * LDSTR + k8] = av[i];
        }
#pragma unroll
        for (int i = 0; i < WCH; ++i) {
            int c = tid + i * NT, r = c >> 2, k8 = (c & 3) << 3;
            *(uint4*)&Ws[r * LDSTR + k8] = wv[i];
        }
        __syncthreads();
        int kn = kt + TK;
        if (kn < K) {                           // next-tile loads hide under MFMA
#pragma unroll
            for (int i = 0; i < ACH; ++i) {
                int c = tid + i * NT, r = c >> 2, k8 = (c & 3) << 3;
                av[i] = (brow + r < n) ? *(const uint4*)(A + (size_t)(brow + r) * lda + kn + k8) : zero4;
            }
#pragma unroll
            for (int i = 0; i < WCH; ++i) {
                int c = tid + i * NT, r = c >> 2, k8 = (c & 3) << 3;
                wv[i] = *(const uint4*)(Wb + (size_t)(bcol + r) * ldw + kn + k8);
            }
        }
        bf16x8 a[4], b[4];
#pragma unroll
        for (int mb = 0; mb < 4; ++mb)
            a[mb] = *(const bf16x8*)&As[(64 * wr + 16 * mb + rsel) * LDSTR + krun];
#pragma unroll
        for (int nb = 0; nb < 4; ++nb)
            b[nb] = *(const bf16x8*)&Ws[(64 * wc + 16 * nb + rsel) * LDSTR + krun];
#pragma unroll
        for (int mb = 0; mb < 4; ++mb)
#pragma unroll
            for (int nb = 0; nb < 4; ++nb)
                acc[mb][nb] = __builtin_amdgcn_mfma_f32_16x16x32_bf16(
                    a[mb], b[nb], acc[mb][nb], 0, 0, 0);
    }
}

// NT threads, TNN = block col-tile (64*NWC). ACCUM: 0 none, 1 from C, 2 from bf16 accBuf
template<int NT, int TNN, int CF32, int RELU, int ACCUM>
__global__ __launch_bounds__(NT)
void gemm_mfma(const u16* __restrict__ A1, int K1, int lda1,
               const u16* __restrict__ W1, int ldw1,
               const u16* __restrict__ A2, int K2, int lda2,
               const u16* __restrict__ W2, int ldw2,
               const float* __restrict__ bias, const u16* __restrict__ accBuf,
               void* __restrict__ C, int n, int cout)
{
    constexpr int NWC = TNN / 64;
    __shared__ u16 As[TM * LDSTR];
    __shared__ u16 Ws[TNN * LDSTR];
    int tid = threadIdx.x;
    int lane = tid & 63, wid = tid >> 6;
    int wr = wid / NWC, wc = wid % NWC;
    int brow = blockIdx.x * TM, bcol = blockIdx.y * TNN;

    f32x4 acc[4][4];
#pragma unroll
    for (int i = 0; i < 4; ++i)
#pragma unroll
        for (int j = 0; j < 4; ++j) acc[i][j] = (f32x4){0.f, 0.f, 0.f, 0.f};

    mfma_pass_bf<NT, TNN>(A1, K1, lda1, W1, ldw1, brow, bcol, n, tid, lane, wr, wc, As, Ws, acc);
    if (K2 > 0)
        mfma_pass_bf<NT, TNN>(A2, K2, lda2, W2, ldw2, brow, bcol, n, tid, lane, wr, wc, As, Ws, acc);

    // epilogue: D col = lane&15, row = 4*(lane>>4)+reg
    int rsel = lane & 15;
    int rgrp = (lane >> 4) << 2;
    float bv[4];
#pragma unroll
    for (int nb = 0; nb < 4; ++nb)
        bv[nb] = bias ? bias[bcol + 64 * wc + 16 * nb + rsel] : 0.f;

#pragma unroll
    for (int mb = 0; mb < 4; ++mb) {
        int rowb = brow + 64 * wr + 16 * mb + rgrp;
#pragma unroll
        for (int r = 0; r < 4; ++r) {
            int row = rowb + r;
            if (row >= n) continue;
            size_t rof = (size_t)row * cout;
#pragma unroll
            for (int nb = 0; nb < 4; ++nb) {
                int col = bcol + 64 * wc + 16 * nb + rsel;
                float v = acc[mb][nb][r] + bv[nb];
                if (ACCUM == 2) v += __uint_as_float(((u32)accBuf[rof + col]) << 16);
                if (CF32) {
                    float* p = (float*)C + rof + col;
                    if (ACCUM == 1) v += *p;
                    if (RELU) v = fmaxf(v, 0.f);
                    *p = v;
                } else {
                    u16* p = (u16*)C + rof + col;
                    if (ACCUM == 1) v += __uint_as_float(((u32)(*p)) << 16);
                    if (RELU) v = fmaxf(v, 0.f);
                    *p = f2bf(v);
                }
            }
        }
    }
}

extern "C" void kernel_launch(void* const* d_in, const int* in_sizes, int n_in,
                              void* d_out, int out_size, void* d_ws, size_t ws_size,
                              hipStream_t stream) {
    const float* x   = (const float*)d_in[0];
    const int*   ei  = (const int*)d_in[1];
    const float* Wl1 = (const float*)d_in[2];
    const float* bl1 = (const float*)d_in[3];
    const float* Wr1 = (const float*)d_in[4];
    const float* Wl2 = (const float*)d_in[5];
    const float* bl2 = (const float*)d_in[6];
    const float* Wr2 = (const float*)d_in[7];
    const float* Wl3 = (const float*)d_in[8];
    const float* bl3 = (const float*)d_in[9];
    const float* Wr3 = (const float*)d_in[10];
    float* out = (float*)d_out;

    const int* src = ei;            // edge_index[0]
    const int* dst = ei + NE;       // edge_index[1]

    // ---- workspace layout (as rounds 12-13) ----
    char* ws = (char*)d_ws;
    int*   fill   = (int*)  (ws + 0);
    float* invdeg = (float*)(ws + 400000);
    int*   csrC   = (int*)  (ws + 800000);
    u16*   Wb     = (u16*)  (ws + 26400000);
    u16*   aggS   = (u16*)  (ws + 26924288);
    u16*   h2     = (u16*)  (ws + 52524288);
    u16*   h1     = (u16*)  (ws + 103724288);
    u16*   agg256 = (u16*)  (ws + 154924288);
    u16*   x_bf   = h2;   // [NN][128]; dead before h2 first written
    u16*   t3     = h1;   // [NN][128]; h1 dead after layer-2 agg+GEMM

    const bool big = ws_size >= 206124288ull;

    u16* wbL1 = Wb + 0;
    u16* wbR1 = Wb + 32768;
    u16* wbL2 = Wb + 65536;
    u16* wbR2 = Wb + 131072;
    u16* wbL3 = Wb + 196608;
    u16* wbR3 = Wb + 229376;

    dim3 b256(256);
    dim3 gN((NN + 255) / 256);
    dim3 gC((NN * 32 + 255) / 256);
    dim3 gW((NN * 64 + 255) / 256);
    const int CHUNKS = (NN + 3) / 4;            // nodes per slice-grid
    dim3 gS4(CHUNKS * 4);                       // NSL=4 sliced agg grid
    dim3 gS8(CHUNKS * 8);                       // NSL=8 sliced agg grid
    dim3 ggL1((NN + TM - 1) / TM, 1);           // 512-thr TN=256
    dim3 gg1((NN + TM - 1) / TM, 1);            // 256-thr TN=128, cout=128
    dim3 gg2f((NN + TM - 1) / TM, 2);           // fallback 256-thr TN=128, cout=256

    // ---- weights -> bf16 (one launch) ----
    hipLaunchKernelGGL(weights_to_bf16, dim3(256), b256, 0, stream,
                       (const float4*)Wl1, (const float4*)Wr1, (const float4*)Wl2,
                       (const float4*)Wr2, (const float4*)Wl3, (const float4*)Wr3,
                       (uint2*)Wb);

    // ---- CSR build ----
    hipMemsetAsync(fill, 0, 400000, stream);
    hipLaunchKernelGGL(csr_build, dim3(2048), b256, 0, stream, src, dst, fill, csrC, NE);
    hipLaunchKernelGGL(invdeg_from_fill, gN, b256, 0, stream, fill, invdeg, NN);

    // ---- x -> bf16 ----
    hipLaunchKernelGGL(f32_to_bf16, gC, b256, 0, stream,
                       (const float4*)x, (uint2*)x_bf, NN * 32);

    // ---- layer 1: aggS = mean(x_bf); h1 = relu(aggS@Wl1^T + x_bf@Wr1^T + bl1) ----
    hipLaunchKernelGGL((agg_sl<4>), gS4, b256, 0, stream,
                       (const uint4*)x_bf, fill, invdeg, csrC, (uint4*)aggS);
    hipLaunchKernelGGL((gemm_mfma<512, 256, 0, 1, 0>), ggL1, dim3(512), 0, stream,
                       aggS, DIN, DIN, wbL1, DIN,
                       x_bf, DIN, DIN, wbR1, DIN,
                       bl1, nullptr, h1, NN, DHID);

    // ---- layer 2 ----
    if (big) {
        hipLaunchKernelGGL((agg_sl<8>), gS8, b256, 0, stream,
                           (const uint4*)h1, fill, invdeg, csrC, (uint4*)agg256);
        hipLaunchKernelGGL((gemm_mfma<512, 256, 0, 1, 0>), ggL1, dim3(512), 0, stream,
                           agg256, DHID, DHID, wbL2, DHID,
                           h1, DHID, DHID, wbR2, DHID,
                           bl2, nullptr, h2, NN, DHID);
    } else {
        hipLaunchKernelGGL((agg_bf16<7, 0>), gW, b256, 0, stream,
                           (const u32*)h1, fill, invdeg, csrC, (u32*)aggS);
        hipLaunchKernelGGL((gemm_mfma<256, 128, 0, 0, 0>), gg2f, b256, 0, stream,
                           aggS, 128, 128, wbL2, DHID,
                           h1, DHID, DHID, wbR2, DHID,
                           bl2, nullptr, h2, NN, DHID);
        hipLaunchKernelGGL((agg_bf16<7, 64>), gW, b256, 0, stream,
                           (const u32*)h1, fill, invdeg, csrC, (u32*)aggS);
        hipLaunchKernelGGL((gemm_mfma<256, 128, 0, 1, 1>), gg2f, b256, 0, stream,
                           aggS, 128, 128, wbL2 + 128, DHID,
                           nullptr, 0, 0, nullptr, 0,
                           nullptr, nullptr, h2, NN, DHID);
    }

    // ---- layer 3 (transform-first): t3 = h2@Wl3^T ; aggS = mean(t3) ;
    //      out = h2@Wr3^T + bl3 + aggS ----
    hipLaunchKernelGGL((gemm_mfma<256, 128, 0, 0, 0>), gg1, b256, 0, stream,
                       h2, DHID, DHID, wbL3, DHID,
                       nullptr, 0, 0, nullptr, 0,
                       nullptr, nullptr, t3, NN, DOUT);
    hipLaunchKernelGGL((agg_sl<4>), gS4, b256, 0, stream,
                       (const uint4*)t3, fill, invdeg, csrC, (uint4*)aggS);
    hipLaunchKernelGGL((gemm_mfma<256, 128, 1, 0, 2>), gg1, b256, 0, stream,
                       h2, DHID, DHID, wbR3, DHID,
                       nullptr, 0, 0, nullptr, 0,
                       bl3, aggS, out, NN, DOUT);
}

// Round 15
// 592.320 us; speedup vs baseline: 1.5920x; 1.5920x over previous
//
#include <hip/hip_runtime.h>

#define NN 100000
#define NE 1600000
#define DIN 128
#define DHID 256
#define DOUT 128
#define CAP 64          // fixed csr row capacity; P(deg>64) ~ 3e-14 for Poisson(16)

typedef unsigned int u32;
typedef unsigned short u16;

typedef __bf16 bf16x8 __attribute__((ext_vector_type(8)));
typedef float  f32x4  __attribute__((ext_vector_type(4)));

__device__ inline u16 f2bf(float f) {
    u32 u = __float_as_uint(f);
    u32 r = u + 0x7FFFu + ((u >> 16) & 1u);   // RTNE
    return (u16)(r >> 16);
}
__device__ inline u32 pack2(float a, float b) {
    return (u32)f2bf(a) | ((u32)f2bf(b) << 16);
}
__device__ inline float bflo(u32 u) { return __uint_as_float(u << 16); }
__device__ inline float bfhi(u32 u) { return __uint_as_float(u & 0xffff0000u); }

// ---------------- CSR build (one-pass, XCD-partitioned, fixed capacity) ----------------
__global__ void csr_build(const int* __restrict__ src, const int* __restrict__ dst,
                          int* __restrict__ fill, int* __restrict__ csrC, int nE) {
    int g  = blockIdx.x & 7;
    int bg = blockIdx.x >> 3;
    int nbg = gridDim.x >> 3;
    int lo = g * (NN / 8), hi = lo + (NN / 8);
    for (int e = bg * 256 + threadIdx.x; e < nE; e += nbg * 256) {
        int d = __builtin_nontemporal_load(dst + e);
        if (d >= lo && d < hi) {
            int pos = atomicAdd(&fill[d], 1);
            if (pos < CAP) csrC[(size_t)d * CAP + pos] = __builtin_nontemporal_load(src + e);
        }
    }
}

__global__ void invdeg_from_fill(const int* __restrict__ fill, float* __restrict__ invdeg, int n) {
    int i = blockIdx.x * 256 + threadIdx.x;
    if (i < n) { int d = fill[i]; invdeg[i] = d > 0 ? 1.0f / (float)d : 0.0f; }
}

// ---------------- conversions ----------------
__global__ void f32_to_bf16(const float4* __restrict__ in, uint2* __restrict__ outp, int total4) {
    int i = blockIdx.x * 256 + threadIdx.x;
    if (i < total4) {
        float4 v = in[i];
        uint2 r; r.x = pack2(v.x, v.y); r.y = pack2(v.z, v.w);
        outp[i] = r;
    }
}

__global__ void weights_to_bf16(const float4* __restrict__ W0, const float4* __restrict__ W1,
                                const float4* __restrict__ W2, const float4* __restrict__ W3,
                                const float4* __restrict__ W4, const float4* __restrict__ W5,
                                uint2* __restrict__ outp) {
    int i = blockIdx.x * 256 + threadIdx.x;
    if (i >= 65536) return;
    const float4* p; int off;
    if (i < 8192)       { p = W0; off = i; }
    else if (i < 16384) { p = W1; off = i - 8192; }
    else if (i < 32768) { p = W2; off = i - 16384; }
    else if (i < 49152) { p = W3; off = i - 32768; }
    else if (i < 57344) { p = W4; off = i - 49152; }
    else                { p = W5; off = i - 57344; }
    float4 v = p[off];
    uint2 r; r.x = pack2(v.x, v.y); r.y = pack2(v.z, v.w);
    outp[i] = r;
}

#define ACC8(A, U) \
    A[0] += bflo(U.x); A[1] += bfhi(U.x); A[2] += bflo(U.y); A[3] += bfhi(U.y); \
    A[4] += bflo(U.z); A[5] += bfhi(U.z); A[6] += bflo(U.w); A[7] += bfhi(U.w);

// ---------------- pull-aggregation (one wave per node), uint4 multi-row (round-13 proven) ----------------
// 128-col rows (16 uint4): 16 lanes/row, 4 rows per load instruction.
__global__ __launch_bounds__(256)
void agg128_u4(const uint4* __restrict__ feat,
               const int* __restrict__ fill, const float* __restrict__ invdeg,
               const int* __restrict__ csrC, uint4* __restrict__ aggOut) {
    int w = (blockIdx.x * 256 + threadIdx.x) >> 6;
    int lane = threadIdx.x & 63;
    if (w >= NN) return;
    int dg = fill[w]; if (dg > CAP) dg = CAP;
    const int* cp = csrC + (size_t)w * CAP;
    int q = lane >> 4, sub = lane & 15;
    float a[8] = {0,0,0,0,0,0,0,0};
    float b[8] = {0,0,0,0,0,0,0,0};
    int j = 0;
    for (; j + 7 < dg; j += 8) {          // 8 rows in flight via 2 loads
        int s0 = cp[j + q], s1 = cp[j + 4 + q];
        uint4 u0 = feat[(size_t)s0 * 16 + sub];
        uint4 u1 = feat[(size_t)s1 * 16 + sub];
        ACC8(a, u0); ACC8(b, u1);
    }
    while (j < dg) {                      // <= 2 masked passes
        if (j + q < dg) {
            int s0 = cp[j + q];
            uint4 u0 = feat[(size_t)s0 * 16 + sub];
            ACC8(a, u0);
        }
        j += 4;
    }
    float iv = invdeg[w];
#pragma unroll
    for (int i = 0; i < 8; ++i) {
        float v = a[i] + b[i];
        v += __shfl_xor(v, 16, 64);
        v += __shfl_xor(v, 32, 64);
        a[i] = v * iv;
    }
    if (q == 0) {
        uint4 r;
        r.x = pack2(a[0], a[1]); r.y = pack2(a[2], a[3]);
        r.z = pack2(a[4], a[5]); r.w = pack2(a[6], a[7]);
        aggOut[(size_t)w * 16 + sub] = r;
    }
}

// 256-col rows (32 uint4): 32 lanes/row, 2 rows per load, 4 loads unrolled.
__global__ __launch_bounds__(256)
void agg256_u4(const uint4* __restrict__ feat,
               const int* __restrict__ fill, const float* __restrict__ invdeg,
               const int* __restrict__ csrC, uint4* __restrict__ aggOut) {
    int w = (blockIdx.x * 256 + threadIdx.x) >> 6;
    int lane = threadIdx.x & 63;
    if (w >= NN) return;
    int dg = fill[w]; if (dg > CAP) dg = CAP;
    const int* cp = csrC + (size_t)w * CAP;
    int h = lane >> 5, sub = lane & 31;
    float a[8] = {0,0,0,0,0,0,0,0};
    float b[8] = {0,0,0,0,0,0,0,0};
    float c[8] = {0,0,0,0,0,0,0,0};
    float d[8] = {0,0,0,0,0,0,0,0};
    int j = 0;
    for (; j + 7 < dg; j += 8) {          // 8 rows in flight via 4 loads
        int s0 = cp[j + h],     s1 = cp[j + 2 + h];
        int s2 = cp[j + 4 + h], s3 = cp[j + 6 + h];
        uint4 u0 = feat[(size_t)s0 * 32 + sub];
        uint4 u1 = feat[(size_t)s1 * 32 + sub];
        uint4 u2 = feat[(size_t)s2 * 32 + sub];
        uint4 u3 = feat[(size_t)s3 * 32 + sub];
        ACC8(a, u0); ACC8(b, u1); ACC8(c, u2); ACC8(d, u3);
    }
    while (j < dg) {                      // <= 4 masked passes
        if (j + h < dg) {
            int s0 = cp[j + h];
            uint4 u0 = feat[(size_t)s0 * 32 + sub];
            ACC8(a, u0);
        }
        j += 2;
    }
    float iv = invdeg[w];
#pragma unroll
    for (int i = 0; i < 8; ++i) {
        float v = (a[i] + b[i]) + (c[i] + d[i]);
        v += __shfl_xor(v, 32, 64);
        a[i] = v * iv;
    }
    if (h == 0) {
        uint4 r;
        r.x = pack2(a[0], a[1]); r.y = pack2(a[2], a[3]);
        r.z = pack2(a[4], a[5]); r.w = pack2(a[6], a[7]);
        aggOut[(size_t)w * 32 + sub] = r;
    }
}

// legacy 128-col gather with column offset (fallback path only)
template<int SH, int OFF>
__global__ __launch_bounds__(256)
void agg_bf16(const u32* __restrict__ feat,
              const int* __restrict__ fill, const float* __restrict__ invdeg,
              const int* __restrict__ csrC, u32* __restrict__ aggOut) {
    int w = (blockIdx.x * 256 + threadIdx.x) >> 6;
    int lane = threadIdx.x & 63;
    if (w >= NN) return;
    int dg = fill[w]; if (dg > CAP) dg = CAP;
    const int* cp = csrC + (size_t)w * CAP;
    float a0 = 0.f, b0 = 0.f, a1 = 0.f, b1 = 0.f;
    int j = 0;
    for (; j + 1 < dg; j += 2) {
        int s0 = cp[j], s1 = cp[j+1];
        u32 u0 = feat[((size_t)s0 << SH) + OFF + lane];
        u32 u1 = feat[((size_t)s1 << SH) + OFF + lane];
        a0 += bflo(u0); b0 += bfhi(u0);
        a1 += bflo(u1); b1 += bfhi(u1);
    }
    if (j < dg) {
        u32 u0 = feat[((size_t)cp[j] << SH) + OFF + lane];
        a0 += bflo(u0); b0 += bfhi(u0);
    }
    float iv = invdeg[w];
    aggOut[(size_t)w * 64 + lane] = pack2((a0 + a1) * iv, (b0 + b1) * iv);
}

// ---------------- MFMA bf16 dual-GEMM (templated block shape) ----------------
#define TM 128
#define TK 32
#define LDSTR 40   // bf16 elems per LDS row: 80 B (16B-aligned, low-conflict)

template<int NT, int TNN>
__device__ inline void mfma_pass_bf(const u16* __restrict__ A, int K, int lda,
                                    const u16* __restrict__ Wb, int ldw,
                                    int brow, int bcol, int n,
                                    int tid, int lane, int wr, int wc,
                                    u16* As, u16* Ws, f32x4 (&acc)[4][4])
{
    constexpr int ACH = (TM * TK) / (8 * NT);   // uint4 chunks per thread for A
    constexpr int WCH = (TNN * TK) / (8 * NT);  // for W
    int rsel = lane & 15;
    int krun = (lane >> 4) << 3;                // 0,8,16,24
    const uint4 zero4 = make_uint4(0u, 0u, 0u, 0u);
    uint4 av[ACH], wv[WCH];

#pragma unroll
    for (int i = 0; i < ACH; ++i) {
        int c = tid + i * NT, r = c >> 2, k8 = (c & 3) << 3;
        av[i] = (brow + r < n) ? *(const uint4*)(A + (size_t)(brow + r) * lda + k8) : zero4;
    }
#pragma unroll
    for (int i = 0; i < WCH; ++i) {
        int c = tid + i * NT, r = c >> 2, k8 = (c & 3) << 3;
        wv[i] = *(const uint4*)(Wb + (size_t)(bcol + r) * ldw + k8);
    }

    for (int kt = 0; kt < K; kt += TK) {
        __syncthreads();                        // prev-iter LDS reads done
#pragma unroll
        for (int i = 0; i < ACH; ++i) {
            int c = tid + i * NT, r = c >> 2, k8 = (c & 3) << 3;
            *(uint4*)&As[r * LDSTR + k8] = av[i];
        }
#pragma unroll
        for (int i = 0; i < WCH; ++i) {
            int c = tid + i * NT, r = c >> 2, k8 = (c & 3) << 3;
            *(uint4*)&Ws[r * LDSTR + k8] = wv[i];
        }
        __syncthreads();
        int kn = kt + TK;
        if (kn < K) {                           // next-tile loads hide under MFMA
#pragma unroll
            for (int i = 0; i < ACH; ++i) {
                int c = tid + i * NT, r = c >> 2, k8 = (c & 3) << 3;
                av[i] = (brow + r < n) ? *(const uint4*)(A + (size_t)(brow + r) * lda + kn + k8) : zero4;
            }
#pragma unroll
            for (int i = 0; i < WCH; ++i) {
                int c = tid + i * NT, r = c >> 2, k8 = (c & 3) << 3;
                wv[i] = *(const uint4*)(Wb + (size_t)(bcol + r) * ldw + kn + k8);
            }
        }
        bf16x8 a[4], b[4];
#pragma unroll
        for (int mb = 0; mb < 4; ++mb)
            a[mb] = *(const bf16x8*)&As[(64 * wr + 16 * mb + rsel) * LDSTR + krun];
#pragma unroll
        for (int nb = 0; nb < 4; ++nb)
            b[nb] = *(const bf16x8*)&Ws[(64 * wc + 16 * nb + rsel) * LDSTR + krun];
#pragma unroll
        for (int mb = 0; mb < 4; ++mb)
#pragma unroll
            for (int nb = 0; nb < 4; ++nb)
                acc[mb][nb] = __builtin_amdgcn_mfma_f32_16x16x32_bf16(
                    a[mb], b[nb], acc[mb][nb], 0, 0, 0);
    }
}

// NT threads, TNN = block col-tile (64*NWC). ACCUM: 0 none, 1 from C, 2 from bf16 accBuf
template<int NT, int TNN, int CF32, int RELU, int ACCUM>
__global__ __launch_bounds__(NT)
void gemm_mfma(const u16* __restrict__ A1, int K1, int lda1,
               const u16* __restrict__ W1, int ldw1,
               const u16* __restrict__ A2, int K2, int lda2,
               const u16* __restrict__ W2, int ldw2,
               const float* __restrict__ bias, const u16* __restrict__ accBuf,
               void* __restrict__ C, int n, int cout)
{
    constexpr int NWC = TNN / 64;
    __shared__ u16 As[TM * LDSTR];
    __shared__ u16 Ws[TNN * LDSTR];
    int tid = threadIdx.x;
    int lane = tid & 63, wid = tid >> 6;
    int wr = wid / NWC, wc = wid % NWC;
    int brow = blockIdx.x * TM, bcol = blockIdx.y * TNN;

    f32x4 acc[4][4];
#pragma unroll
    for (int i = 0; i < 4; ++i)
#pragma unroll
        for (int j = 0; j < 4; ++j) acc[i][j] = (f32x4){0.f, 0.f, 0.f, 0.f};

    mfma_pass_bf<NT, TNN>(A1, K1, lda1, W1, ldw1, brow, bcol, n, tid, lane, wr, wc, As, Ws, acc);
    if (K2 > 0)
        mfma_pass_bf<NT, TNN>(A2, K2, lda2, W2, ldw2, brow, bcol, n, tid, lane, wr, wc, As, Ws, acc);

    // epilogue: D col = lane&15, row = 4*(lane>>4)+reg
    int rsel = lane & 15;
    int rgrp = (lane >> 4) << 2;
    float bv[4];
#pragma unroll
    for (int nb = 0; nb < 4; ++nb)
        bv[nb] = bias ? bias[bcol + 64 * wc + 16 * nb + rsel] : 0.f;

#pragma unroll
    for (int mb = 0; mb < 4; ++mb) {
        int rowb = brow + 64 * wr + 16 * mb + rgrp;
#pragma unroll
        for (int r = 0; r < 4; ++r) {
            int row = rowb + r;
            if (row >= n) continue;
            size_t rof = (size_t)row * cout;
#pragma unroll
            for (int nb = 0; nb < 4; ++nb) {
                int col = bcol + 64 * wc + 16 * nb + rsel;
                float v = acc[mb][nb][r] + bv[nb];
                if (ACCUM == 2) v += __uint_as_float(((u32)accBuf[rof + col]) << 16);
                if (CF32) {
                    float* p = (float*)C + rof + col;
                    if (ACCUM == 1) v += *p;
                    if (RELU) v = fmaxf(v, 0.f);
                    *p = v;
                } else {
                    u16* p = (u16*)C + rof + col;
                    if (ACCUM == 1) v += __uint_as_float(((u32)(*p)) << 16);
                    if (RELU) v = fmaxf(v, 0.f);
                    *p = f2bf(v);
                }
            }
        }
    }
}

extern "C" void kernel_launch(void* const* d_in, const int* in_sizes, int n_in,
                              void* d_out, int out_size, void* d_ws, size_t ws_size,
                              hipStream_t stream) {
    const float* x   = (const float*)d_in[0];
    const int*   ei  = (const int*)d_in[1];
    const float* Wl1 = (const float*)d_in[2];
    const float* bl1 = (const float*)d_in[3];
    const float* Wr1 = (const float*)d_in[4];
    const float* Wl2 = (const float*)d_in[5];
    const float* bl2 = (const float*)d_in[6];
    const float* Wr2 = (const float*)d_in[7];
    const float* Wl3 = (const float*)d_in[8];
    const float* bl3 = (const float*)d_in[9];
    const float* Wr3 = (const float*)d_in[10];
    float* out = (float*)d_out;

    const int* src = ei;            // edge_index[0]
    const int* dst = ei + NE;       // edge_index[1]

    // ---- workspace layout (as rounds 12-13) ----
    char* ws = (char*)d_ws;
    int*   fill   = (int*)  (ws + 0);
    float* invdeg = (float*)(ws + 400000);
    int*   csrC   = (int*)  (ws + 800000);
    u16*   Wb     = (u16*)  (ws + 26400000);
    u16*   aggS   = (u16*)  (ws + 26924288);
    u16*   h2     = (u16*)  (ws + 52524288);
    u16*   h1     = (u16*)  (ws + 103724288);
    u16*   agg256 = (u16*)  (ws + 154924288);
    u16*   x_bf   = h2;   // [NN][128]; dead before h2 first written
    u16*   t3     = h1;   // [NN][128]; h1 dead after layer-2 agg+GEMM

    const bool big = ws_size >= 206124288ull;

    u16* wbL1 = Wb + 0;
    u16* wbR1 = Wb + 32768;
    u16* wbL2 = Wb + 65536;
    u16* wbR2 = Wb + 131072;
    u16* wbL3 = Wb + 196608;
    u16* wbR3 = Wb + 229376;

    dim3 b256(256);
    dim3 gN((NN + 255) / 256);
    dim3 gC((NN * 32 + 255) / 256);
    dim3 gW((NN * 64 + 255) / 256);             // one wave per node
    dim3 ggL1((NN + TM - 1) / TM, 1);           // 512-thr TN=256
    dim3 gg1((NN + TM - 1) / TM, 1);            // 256-thr TN=128, cout=128
    dim3 gg2f((NN + TM - 1) / TM, 2);           // fallback 256-thr TN=128, cout=256

    // ---- weights -> bf16 (one launch) ----
    hipLaunchKernelGGL(weights_to_bf16, dim3(256), b256, 0, stream,
                       (const float4*)Wl1, (const float4*)Wr1, (const float4*)Wl2,
                       (const float4*)Wr2, (const float4*)Wl3, (const float4*)Wr3,
                       (uint2*)Wb);

    // ---- CSR build ----
    hipMemsetAsync(fill, 0, 400000, stream);
    hipLaunchKernelGGL(csr_build, dim3(2048), b256, 0, stream, src, dst, fill, csrC, NE);
    hipLaunchKernelGGL(invdeg_from_fill, gN, b256, 0, stream, fill, invdeg, NN);

    // ---- x -> bf16 ----
    hipLaunchKernelGGL(f32_to_bf16, gC, b256, 0, stream,
                       (const float4*)x, (uint2*)x_bf, NN * 32);

    // ---- layer 1: aggS = mean(x_bf); h1 = relu(aggS@Wl1^T + x_bf@Wr1^T + bl1) ----
    hipLaunchKernelGGL(agg128_u4, gW, b256, 0, stream,
                       (const uint4*)x_bf, fill, invdeg, csrC, (uint4*)aggS);
    hipLaunchKernelGGL((gemm_mfma<512, 256, 0, 1, 0>), ggL1, dim3(512), 0, stream,
                       aggS, DIN, DIN, wbL1, DIN,
                       x_bf, DIN, DIN, wbR1, DIN,
                       bl1, nullptr, h1, NN, DHID);

    // ---- layer 2 ----
    if (big) {
        hipLaunchKernelGGL(agg256_u4, gW, b256, 0, stream,
                           (const uint4*)h1, fill, invdeg, csrC, (uint4*)agg256);
        hipLaunchKernelGGL((gemm_mfma<512, 256, 0, 1, 0>), ggL1, dim3(512), 0, stream,
                           agg256, DHID, DHID, wbL2, DHID,
                           h1, DHID, DHID, wbR2, DHID,
                           bl2, nullptr, h2, NN, DHID);
    } else {
        hipLaunchKernelGGL((agg_bf16<7, 0>), gW, b256, 0, stream,
                           (const u32*)h1, fill, invdeg, csrC, (u32*)aggS);
        hipLaunchKernelGGL((gemm_mfma<256, 128, 0, 0, 0>), gg2f, b256, 0, stream,
                           aggS, 128, 128, wbL2, DHID,
                           h1, DHID, DHID, wbR2, DHID,
                           bl2, nullptr, h2, NN, DHID);
        hipLaunchKernelGGL((agg_bf16<7, 64>), gW, b256, 0, stream,
                           (const u32*)h1, fill, invdeg, csrC, (u32*)aggS);
        hipLaunchKernelGGL((gemm_mfma<256, 128, 0, 1, 1>), gg2f, b256, 0, stream,
                           aggS, 128, 128, wbL2 + 128, DHID,
                           nullptr, 0, 0, nullptr, 0,
                           nullptr, nullptr, h2, NN, DHID);
    }

    // ---- layer 3 (transform-first): t3 = h2@Wl3^T ; aggS = mean(t3) ;
    //      out = h2@Wr3^T + bl3 + aggS ----
    hipLaunchKernelGGL((gemm_mfma<256, 128, 0, 0, 0>), gg1, b256, 0, stream,
                       h2, DHID, DHID, wbL3, DHID,
                       nullptr, 0, 0, nullptr, 0,
                       nullptr, nullptr, t3, NN, DOUT);
    hipLaunchKernelGGL(agg128_u4, gW, b256, 0, stream,
                       (const uint4*)t3, fill, invdeg, csrC, (uint4*)aggS);
    hipLaunchKernelGGL((gemm_mfma<256, 128, 1, 0, 2>), gg1, b256, 0, stream,
                       h2, DHID, DHID, wbR3, DHID,
                       nullptr, 0, 0, nullptr, 0,
                       bl3, aggS, out, NN, DOUT);
}

// Round 16
// 474.644 us; speedup vs baseline: 1.9867x; 1.2479x over previous
//
#include <hip/hip_runtime.h>

#define NN 100000
#define NE 1600000
#define DIN 128
#define DHID 256
#define DOUT 128
#define CAP 64          // fixed csr row capacity; P(deg>64) ~ 3e-14 for Poisson(16)

typedef unsigned int u32;
typedef unsigned short u16;

typedef __bf16 bf16x8 __attribute__((ext_vector_type(8)));
typedef float  f32x4  __attribute__((ext_vector_type(4)));

__device__ inline u16 f2bf(float f) {
    u32 u = __float_as_uint(f);
    u32 r = u + 0x7FFFu + ((u >> 16) & 1u);   // RTNE
    return (u16)(r >> 16);
}
__device__ inline u32 pack2(float a, float b) {
    return (u32)f2bf(a) | ((u32)f2bf(b) << 16);
}
__device__ inline float bflo(u32 u) { return __uint_as_float(u << 16); }
__device__ inline float bfhi(u32 u) { return __uint_as_float(u & 0xffff0000u); }

// ---------------- CSR build (one-pass, XCD-partitioned, fixed capacity) ----------------
__global__ void csr_build(const int* __restrict__ src, const int* __restrict__ dst,
                          int* __restrict__ fill, int* __restrict__ csrC, int nE) {
    int g  = blockIdx.x & 7;
    int bg = blockIdx.x >> 3;
    int nbg = gridDim.x >> 3;
    int lo = g * (NN / 8), hi = lo + (NN / 8);
    for (int e = bg * 256 + threadIdx.x; e < nE; e += nbg * 256) {
        int d = __builtin_nontemporal_load(dst + e);
        if (d >= lo && d < hi) {
            int pos = atomicAdd(&fill[d], 1);
            if (pos < CAP) csrC[(size_t)d * CAP + pos] = __builtin_nontemporal_load(src + e);
        }
    }
}

// ---------------- combined conversion: x (NN*32 float4) + 6 weight mats (65536 float4) ----------------
__global__ void conv_all(const float4* __restrict__ x,
                         const float4* __restrict__ W0, const float4* __restrict__ W1,
                         const float4* __restrict__ W2, const float4* __restrict__ W3,
                         const float4* __restrict__ W4, const float4* __restrict__ W5,
                         uint2* __restrict__ x_out, uint2* __restrict__ w_out) {
    int i = blockIdx.x * 256 + threadIdx.x;
    const int XT = NN * 32;
    if (i < XT) {
        float4 v = x[i];
        uint2 r; r.x = pack2(v.x, v.y); r.y = pack2(v.z, v.w);
        x_out[i] = r;
        return;
    }
    int j = i - XT;
    if (j >= 65536) return;
    const float4* p; int off;
    if (j < 8192)       { p = W0; off = j; }
    else if (j < 16384) { p = W1; off = j - 8192; }
    else if (j < 32768) { p = W2; off = j - 16384; }
    else if (j < 49152) { p = W3; off = j - 32768; }
    else if (j < 57344) { p = W4; off = j - 49152; }
    else                { p = W5; off = j - 57344; }
    float4 v = p[off];
    uint2 r; r.x = pack2(v.x, v.y); r.y = pack2(v.z, v.w);
    w_out[j] = r;
}

#define ACC8(A, U) \
    A[0] += bflo(U.x); A[1] += bfhi(U.x); A[2] += bflo(U.y); A[3] += bfhi(U.y); \
    A[4] += bflo(U.z); A[5] += bfhi(U.z); A[6] += bflo(U.w); A[7] += bfhi(U.w);

// ---------------- pull-aggregation (one wave per node), uint4 multi-row (round-13 proven) ----------------
// 128-col rows (16 uint4): 16 lanes/row, 4 rows per load instruction.
__global__ __launch_bounds__(256)
void agg128_u4(const uint4* __restrict__ feat,
               const int* __restrict__ fill,
               const int* __restrict__ csrC, uint4* __restrict__ aggOut) {
    int w = (blockIdx.x * 256 + threadIdx.x) >> 6;
    int lane = threadIdx.x & 63;
    if (w >= NN) return;
    int dgt = fill[w];
    float iv = dgt > 0 ? 1.0f / (float)dgt : 0.0f;
    int dg = dgt > CAP ? CAP : dgt;
    const int* cp = csrC + (size_t)w * CAP;
    int q = lane >> 4, sub = lane & 15;
    float a[8] = {0,0,0,0,0,0,0,0};
    float b[8] = {0,0,0,0,0,0,0,0};
    int j = 0;
    for (; j + 7 < dg; j += 8) {          // 8 rows in flight via 2 loads
        int s0 = cp[j + q], s1 = cp[j + 4 + q];
        uint4 u0 = feat[(size_t)s0 * 16 + sub];
        uint4 u1 = feat[(size_t)s1 * 16 + sub];
        ACC8(a, u0); ACC8(b, u1);
    }
    while (j < dg) {                      // <= 2 masked passes
        if (j + q < dg) {
            int s0 = cp[j + q];
            uint4 u0 = feat[(size_t)s0 * 16 + sub];
            ACC8(a, u0);
        }
        j += 4;
    }
#pragma unroll
    for (int i = 0; i < 8; ++i) {
        float v = a[i] + b[i];
        v += __shfl_xor(v, 16, 64);
        v += __shfl_xor(v, 32, 64);
        a[i] = v * iv;
    }
    if (q == 0) {
        uint4 r;
        r.x = pack2(a[0], a[1]); r.y = pack2(a[2], a[3]);
        r.z = pack2(a[4], a[5]); r.w = pack2(a[6], a[7]);
        aggOut[(size_t)w * 16 + sub] = r;
    }
}

// 256-col rows (32 uint4): 32 lanes/row, 2 rows per load, 4 loads unrolled.
__global__ __launch_bounds__(256)
void agg256_u4(const uint4* __restrict__ feat,
               const int* __restrict__ fill,
               const int* __restrict__ csrC, uint4* __restrict__ aggOut) {
    int w = (blockIdx.x * 256 + threadIdx.x) >> 6;
    int lane = threadIdx.x & 63;
    if (w >= NN) return;
    int dgt = fill[w];
    float iv = dgt > 0 ? 1.0f / (float)dgt : 0.0f;
    int dg = dgt > CAP ? CAP : dgt;
    const int* cp = csrC + (size_t)w * CAP;
    int h = lane >> 5, sub = lane & 31;
    float a[8] = {0,0,0,0,0,0,0,0};
    float b[8] = {0,0,0,0,0,0,0,0};
    float c[8] = {0,0,0,0,0,0,0,0};
    float d[8] = {0,0,0,0,0,0,0,0};
    int j = 0;
    for (; j + 7 < dg; j += 8) {          // 8 rows in flight via 4 loads
        int s0 = cp[j + h],     s1 = cp[j + 2 + h];
        int s2 = cp[j + 4 + h], s3 = cp[j + 6 + h];
        uint4 u0 = feat[(size_t)s0 * 32 + sub];
        uint4 u1 = feat[(size_t)s1 * 32 + sub];
        uint4 u2 = feat[(size_t)s2 * 32 + sub];
        uint4 u3 = feat[(size_t)s3 * 32 + sub];
        ACC8(a, u0); ACC8(b, u1); ACC8(c, u2); ACC8(d, u3);
    }
    while (j < dg) {                      // <= 4 masked passes
        if (j + h < dg) {
            int s0 = cp[j + h];
            uint4 u0 = feat[(size_t)s0 * 32 + sub];
            ACC8(a, u0);
        }
        j += 2;
    }
#pragma unroll
    for (int i = 0; i < 8; ++i) {
        float v = (a[i] + b[i]) + (c[i] + d[i]);
        v += __shfl_xor(v, 32, 64);
        a[i] = v * iv;
    }
    if (h == 0) {
        uint4 r;
        r.x = pack2(a[0], a[1]); r.y = pack2(a[2], a[3]);
        r.z = pack2(a[4], a[5]); r.w = pack2(a[6], a[7]);
        aggOut[(size_t)w * 32 + sub] = r;
    }
}

// legacy 128-col gather with column offset (fallback path only)
template<int SH, int OFF>
__global__ __launch_bounds__(256)
void agg_bf16(const u32* __restrict__ feat,
              const int* __restrict__ fill,
              const int* __restrict__ csrC, u32* __restrict__ aggOut) {
    int w = (blockIdx.x * 256 + threadIdx.x) >> 6;
    int lane = threadIdx.x & 63;
    if (w >= NN) return;
    int dgt = fill[w];
    float iv = dgt > 0 ? 1.0f / (float)dgt : 0.0f;
    int dg = dgt > CAP ? CAP : dgt;
    const int* cp = csrC + (size_t)w * CAP;
    float a0 = 0.f, b0 = 0.f, a1 = 0.f, b1 = 0.f;
    int j = 0;
    for (; j + 1 < dg; j += 2) {
        int s0 = cp[j], s1 = cp[j+1];
        u32 u0 = feat[((size_t)s0 << SH) + OFF + lane];
        u32 u1 = feat[((size_t)s1 << SH) + OFF + lane];
        a0 += bflo(u0); b0 += bfhi(u0);
        a1 += bflo(u1); b1 += bfhi(u1);
    }
    if (j < dg) {
        u32 u0 = feat[((size_t)cp[j] << SH) + OFF + lane];
        a0 += bflo(u0); b0 += bfhi(u0);
    }
    aggOut[(size_t)w * 64 + lane] = pack2((a0 + a1) * iv, (b0 + b1) * iv);
}

// ---------------- MFMA bf16 dual-GEMM (round-13 proven: 256 thr, TM=TN=128, reg-prefetch) ----------------
#define TM 128
#define TN 128
#define TK 32
#define LDSTR 40   // bf16 elems per LDS row: 80 B (16B-aligned, low-conflict)

__device__ inline void mfma_pass_bf(const u16* __restrict__ A, int K, int lda,
                                    const u16* __restrict__ Wb, int ldw,
                                    int brow, int bcol, int n,
                                    int tid, int lane, int wr, int wc,
                                    u16* As, u16* Ws, f32x4 (&acc)[4][4])
{
    int rsel = lane & 15;
    int krun = (lane >> 4) << 3;                  // 0,8,16,24
    int r0 = tid >> 2,         k80 = (tid & 3) << 3;
    int r1 = (tid + 256) >> 2, k81 = k80;
    uint4 av0, av1, wv0, wv1;
    const uint4 zero4 = make_uint4(0u, 0u, 0u, 0u);

    av0 = (brow + r0 < n) ? *(const uint4*)(A + (size_t)(brow + r0) * lda + k80) : zero4;
    av1 = (brow + r1 < n) ? *(const uint4*)(A + (size_t)(brow + r1) * lda + k81) : zero4;
    wv0 = *(const uint4*)(Wb + (size_t)(bcol + r0) * ldw + k80);
    wv1 = *(const uint4*)(Wb + (size_t)(bcol + r1) * ldw + k81);

    for (int kt = 0; kt < K; kt += TK) {
        __syncthreads();                          // prev-iter LDS reads done
        *(uint4*)&As[r0 * LDSTR + k80] = av0;
        *(uint4*)&As[r1 * LDSTR + k81] = av1;
        *(uint4*)&Ws[r0 * LDSTR + k80] = wv0;
        *(uint4*)&Ws[r1 * LDSTR + k81] = wv1;
        __syncthreads();
        int kn = kt + TK;
        if (kn < K) {                             // next-tile loads hide under MFMA
            av0 = (brow + r0 < n) ? *(const uint4*)(A + (size_t)(brow + r0) * lda + kn + k80) : zero4;
            av1 = (brow + r1 < n) ? *(const uint4*)(A + (size_t)(brow + r1) * lda + kn + k81) : zero4;
            wv0 = *(const uint4*)(Wb + (size_t)(bcol + r0) * ldw + kn + k80);
            wv1 = *(const uint4*)(Wb + (size_t)(bcol + r1) * ldw + kn + k81);
        }
        bf16x8 a[4], b[4];
#pragma unroll
        for (int mb = 0; mb < 4; ++mb)
            a[mb] = *(const bf16x8*)&As[(64 * wr + 16 * mb + rsel) * LDSTR + krun];
#pragma unroll
        for (int nb = 0; nb < 4; ++nb)
            b[nb] = *(const bf16x8*)&Ws[(64 * wc + 16 * nb + rsel) * LDSTR + krun];
#pragma unroll
        for (int mb = 0; mb < 4; ++mb)
#pragma unroll
            for (int nb = 0; nb < 4; ++nb)
                acc[mb][nb] = __builtin_amdgcn_mfma_f32_16x16x32_bf16(
                    a[mb], b[nb], acc[mb][nb], 0, 0, 0);
    }
}

// ACCUM: 0 = none, 1 = accumulate from C itself, 2 = accumulate from bf16 accBuf
template<int CF32, int RELU, int ACCUM>
__global__ __launch_bounds__(256)
void gemm_mfma(const u16* __restrict__ A1, int K1, int lda1,
               const u16* __restrict__ W1, int ldw1,
               const u16* __restrict__ A2, int K2, int lda2,
               const u16* __restrict__ W2, int ldw2,
               const float* __restrict__ bias, const u16* __restrict__ accBuf,
               void* __restrict__ C, int n, int cout)
{
    __shared__ u16 As[TM * LDSTR];
    __shared__ u16 Ws[TN * LDSTR];
    int tid = threadIdx.x;
    int lane = tid & 63, wid = tid >> 6;
    int wr = wid >> 1, wc = wid & 1;
    int brow = blockIdx.x * TM, bcol = blockIdx.y * TN;

    f32x4 acc[4][4];
#pragma unroll
    for (int i = 0; i < 4; ++i)
#pragma unroll
        for (int j = 0; j < 4; ++j) acc[i][j] = (f32x4){0.f, 0.f, 0.f, 0.f};

    mfma_pass_bf(A1, K1, lda1, W1, ldw1, brow, bcol, n, tid, lane, wr, wc, As, Ws, acc);
    if (K2 > 0)
        mfma_pass_bf(A2, K2, lda2, W2, ldw2, brow, bcol, n, tid, lane, wr, wc, As, Ws, acc);

    // epilogue: D col = lane&15, row = 4*(lane>>4)+reg
    int rsel = lane & 15;
    int rgrp = (lane >> 4) << 2;
    float bv[4];
#pragma unroll
    for (int nb = 0; nb < 4; ++nb)
        bv[nb] = bias ? bias[bcol + 64 * wc + 16 * nb + rsel] : 0.f;

#pragma unroll
    for (int mb = 0; mb < 4; ++mb) {
        int rowb = brow + 64 * wr + 16 * mb + rgrp;
#pragma unroll
        for (int r = 0; r < 4; ++r) {
            int row = rowb + r;
            if (row >= n) continue;
            size_t rof = (size_t)row * cout;
#pragma unroll
            for (int nb = 0; nb < 4; ++nb) {
                int col = bcol + 64 * wc + 16 * nb + rsel;
                float v = acc[mb][nb][r] + bv[nb];
                if (ACCUM == 2) v += __uint_as_float(((u32)accBuf[rof + col]) << 16);
                if (CF32) {
                    float* p = (float*)C + rof + col;
                    if (ACCUM == 1) v += *p;
                    if (RELU) v = fmaxf(v, 0.f);
                    *p = v;
                } else {
                    u16* p = (u16*)C + rof + col;
                    if (ACCUM == 1) v += __uint_as_float(((u32)(*p)) << 16);
                    if (RELU) v = fmaxf(v, 0.f);
                    *p = f2bf(v);
                }
            }
        }
    }
}

extern "C" void kernel_launch(void* const* d_in, const int* in_sizes, int n_in,
                              void* d_out, int out_size, void* d_ws, size_t ws_size,
                              hipStream_t stream) {
    const float* x   = (const float*)d_in[0];
    const int*   ei  = (const int*)d_in[1];
    const float* Wl1 = (const float*)d_in[2];
    const float* bl1 = (const float*)d_in[3];
    const float* Wr1 = (const float*)d_in[4];
    const float* Wl2 = (const float*)d_in[5];
    const float* bl2 = (const float*)d_in[6];
    const float* Wr2 = (const float*)d_in[7];
    const float* Wl3 = (const float*)d_in[8];
    const float* bl3 = (const float*)d_in[9];
    const float* Wr3 = (const float*)d_in[10];
    float* out = (float*)d_out;

    const int* src = ei;            // edge_index[0]
    const int* dst = ei + NE;       // edge_index[1]

    // ---- workspace layout (as rounds 12-13; invdeg slot retired but offsets kept) ----
    char* ws = (char*)d_ws;
    int*   fill   = (int*)  (ws + 0);
    int*   csrC   = (int*)  (ws + 800000);
    u16*   Wb     = (u16*)  (ws + 26400000);
    u16*   aggS   = (u16*)  (ws + 26924288);
    u16*   h2     = (u16*)  (ws + 52524288);
    u16*   h1     = (u16*)  (ws + 103724288);
    u16*   agg256 = (u16*)  (ws + 154924288);
    u16*   x_bf   = h2;   // [NN][128]; dead before h2 first written
    u16*   t3     = h1;   // [NN][128]; h1 dead after layer-2 agg+GEMM

    const bool big = ws_size >= 206124288ull;

    u16* wbL1 = Wb + 0;
    u16* wbR1 = Wb + 32768;
    u16* wbL2 = Wb + 65536;
    u16* wbR2 = Wb + 131072;
    u16* wbL3 = Wb + 196608;
    u16* wbR3 = Wb + 229376;

    dim3 b256(256);
    dim3 gW((NN * 64 + 255) / 256);             // one wave per node
    dim3 gConv((NN * 32 + 65536 + 255) / 256);  // x + weights conversion
    dim3 gg2((NN + TM - 1) / TM, DHID / TN);    // cout=256
    dim3 gg1((NN + TM - 1) / TM, DOUT / TN);    // cout=128

    // ---- conversions (x + all weights, one launch) ----
    hipLaunchKernelGGL(conv_all, gConv, b256, 0, stream,
                       (const float4*)x,
                       (const float4*)Wl1, (const float4*)Wr1, (const float4*)Wl2,
                       (const float4*)Wr2, (const float4*)Wl3, (const float4*)Wr3,
                       (uint2*)x_bf, (uint2*)Wb);

    // ---- CSR build ----
    hipMemsetAsync(fill, 0, 400000, stream);
    hipLaunchKernelGGL(csr_build, dim3(2048), b256, 0, stream, src, dst, fill, csrC, NE);

    // ---- layer 1: aggS = mean(x_bf); h1 = relu(aggS@Wl1^T + x_bf@Wr1^T + bl1) ----
    hipLaunchKernelGGL(agg128_u4, gW, b256, 0, stream,
                       (const uint4*)x_bf, fill, csrC, (uint4*)aggS);
    hipLaunchKernelGGL((gemm_mfma<0, 1, 0>), gg2, b256, 0, stream,
                       aggS, DIN, DIN, wbL1, DIN,
                       x_bf, DIN, DIN, wbR1, DIN,
                       bl1, nullptr, h1, NN, DHID);

    // ---- layer 2 ----
    if (big) {
        hipLaunchKernelGGL(agg256_u4, gW, b256, 0, stream,
                           (const uint4*)h1, fill, csrC, (uint4*)agg256);
        hipLaunchKernelGGL((gemm_mfma<0, 1, 0>), gg2, b256, 0, stream,
                           agg256, DHID, DHID, wbL2, DHID,
                           h1, DHID, DHID, wbR2, DHID,
                           bl2, nullptr, h2, NN, DHID);
    } else {
        hipLaunchKernelGGL((agg_bf16<7, 0>), gW, b256, 0, stream,
                           (const u32*)h1, fill, csrC, (u32*)aggS);
        hipLaunchKernelGGL((gemm_mfma<0, 0, 0>), gg2, b256, 0, stream,
                           aggS, 128, 128, wbL2, DHID,
                           h1, DHID, DHID, wbR2, DHID,
                           bl2, nullptr, h2, NN, DHID);
        hipLaunchKernelGGL((agg_bf16<7, 64>), gW, b256, 0, stream,
                           (const u32*)h1, fill, csrC, (u32*)aggS);
        hipLaunchKernelGGL((gemm_mfma<0, 1, 1>), gg2, b256, 0, stream,
                           aggS, 128, 128, wbL2 + 128, DHID,
                           nullptr, 0, 0, nullptr, 0,
                           nullptr, nullptr, h2, NN, DHID);
    }

    // ---- layer 3 (transform-first): t3 = h2@Wl3^T ; aggS = mean(t3) ;
    //      out = h2@Wr3^T + bl3 + aggS ----
    hipLaunchKernelGGL((gemm_mfma<0, 0, 0>), gg1, b256, 0, stream,
                       h2, DHID, DHID, wbL3, DHID,
                       nullptr, 0, 0, nullptr, 0,
                       nullptr, nullptr, t3, NN, DOUT);
    hipLaunchKernelGGL(agg128_u4, gW, b256, 0, stream,
                       (const uint4*)t3, fill, csrC, (uint4*)aggS);
    hipLaunchKernelGGL((gemm_mfma<1, 0, 2>), gg1, b256, 0, stream,
                       h2, DHID, DHID, wbR3, DHID,
                       nullptr, 0, 0, nullptr, 0,
                       bl3, aggS, out, NN, DOUT);
}